// Round 4
// baseline (574.492 us; speedup 1.0000x reference)
//
#include <hip/hip_runtime.h>

#define RES 512
#define NPIX (RES * RES)   // 262144 texels per plane
#define CH 32
#define NBIN 64            // 4x4x4 morton bins (6-bit key), 128-texel cells
#define BCAP 34816         // bin capacity; mean 32768, sigma~181 -> mean+11sigma
#define PPB 2048           // points per scatter block (8 per thread)
#define CPAD 32            // u32 padding per global counter (128 B line each)
#define CHUNKS 136         // BCAP / 256
#define BPX 8              // bins per XCD (NBIN / 8)

typedef float f32x4 __attribute__((ext_vector_type(4)));
typedef float f32x8 __attribute__((ext_vector_type(8)));
typedef _Float16 f16x8 __attribute__((ext_vector_type(8)));

// ---------------------------------------------------------------------------
// Shared bilinear sampler: accumulates all 3 planes for one (point, c8) lane.
// Arithmetic identical to the verified round-0 kernel (absmax unchanged).
// ---------------------------------------------------------------------------
__device__ __forceinline__ f32x8 triplane_sample(
    const _Float16* __restrict__ tp, float cx, float cy, float cz, int c8)
{
    // plane 0 (T_xy): W<-x H<-y ; plane 1 (T_yz): W<-y H<-z ; plane 2 (T_zx): W<-z H<-x
    float wcoord[3] = {cx, cy, cz};
    float hcoord[3] = {cy, cz, cx};
    f32x8 acc = {0.f, 0.f, 0.f, 0.f, 0.f, 0.f, 0.f, 0.f};

    #pragma unroll
    for (int pl = 0; pl < 3; ++pl) {
        const _Float16* __restrict__ tpp = tp + (size_t)pl * NPIX * CH;
        float fx = (wcoord[pl] + 1.0f) * (0.5f * RES) - 0.5f;
        float fy = (hcoord[pl] + 1.0f) * (0.5f * RES) - 0.5f;
        float x0 = floorf(fx), y0 = floorf(fy);
        float wx1 = fx - x0, wy1 = fy - y0;
        float wx0 = 1.0f - wx1, wy0 = 1.0f - wy1;
        int ix0 = (int)x0, iy0 = (int)y0;
        int ix1 = ix0 + 1, iy1 = iy0 + 1;
        if (ix0 < 0 || ix0 >= RES) wx0 = 0.0f;
        if (ix1 < 0 || ix1 >= RES) wx1 = 0.0f;
        if (iy0 < 0 || iy0 >= RES) wy0 = 0.0f;
        if (iy1 < 0 || iy1 >= RES) wy1 = 0.0f;
        int jx0 = min(max(ix0, 0), RES - 1);
        int jx1 = min(max(ix1, 0), RES - 1);
        int jy0 = min(max(iy0, 0), RES - 1);
        int jy1 = min(max(iy1, 0), RES - 1);

        const f16x8* r0 = (const f16x8*)(tpp + (size_t)(jy0 * RES) * CH) + c8;
        const f16x8* r1 = (const f16x8*)(tpp + (size_t)(jy1 * RES) * CH) + c8;
        f16x8 v00 = r0[jx0 * (CH / 8)];
        f16x8 v01 = r0[jx1 * (CH / 8)];
        f16x8 v10 = r1[jx0 * (CH / 8)];
        f16x8 v11 = r1[jx1 * (CH / 8)];

        acc += (wy0 * wx0) * __builtin_convertvector(v00, f32x8)
             + (wy0 * wx1) * __builtin_convertvector(v01, f32x8)
             + (wy1 * wx0) * __builtin_convertvector(v10, f32x8)
             + (wy1 * wx1) * __builtin_convertvector(v11, f32x8);
    }
    return acc;
}

__device__ __forceinline__ void store_point(
    float* __restrict__ out, int oid, int c8, f32x8 acc)
{
    float* op = out + (size_t)oid * CH + c8 * 8;
    f32x4 lo = {acc.s0, acc.s1, acc.s2, acc.s3};
    f32x4 hi = {acc.s4, acc.s5, acc.s6, acc.s7};
    __builtin_nontemporal_store(lo, (f32x4*)op);
    __builtin_nontemporal_store(hi, (f32x4*)(op + 4));
}

// 6-bit morton key: 2 bits/axis over 4x4x4 bins.
__device__ __forceinline__ uint32_t morton6(float x, float y, float z)
{
    int xi = min(max((int)((x + 1.0f) * 2.0f), 0), 3);
    int yi = min(max((int)((y + 1.0f) * 2.0f), 0), 3);
    int zi = min(max((int)((z + 1.0f) * 2.0f), 0), 3);
    uint32_t k = 0;
    #pragma unroll
    for (int b = 0; b < 2; ++b) {
        k |= ((uint32_t)((xi >> b) & 1)) << (3 * b + 0);
        k |= ((uint32_t)((yi >> b) & 1)) << (3 * b + 1);
        k |= ((uint32_t)((zi >> b) & 1)) << (3 * b + 2);
    }
    return k;
}

// ---------------------------------------------------------------------------
// Transpose tile body: (C,H,W) fp32 -> (H,W,C) fp16, 32 ch x 128 px per block.
// ---------------------------------------------------------------------------
__device__ __forceinline__ void transpose_tile(
    const float* __restrict__ in, _Float16* __restrict__ o, int pix0, int t,
    float tile[CH][129])
{
    f32x4 v[4];
    #pragma unroll
    for (int i = 0; i < 4; ++i) {
        int idx = t + i * 256;       // 0..1023
        int c   = idx >> 5;          // 0..31
        int p4  = idx & 31;          // float4 index within 128 pixels
        v[i] = *(const f32x4*)(in + (size_t)c * NPIX + pix0 + p4 * 4);
    }
    #pragma unroll
    for (int i = 0; i < 4; ++i) {
        int idx = t + i * 256;
        int c   = idx >> 5;
        int p4  = idx & 31;
        tile[c][p4 * 4 + 0] = v[i].x;
        tile[c][p4 * 4 + 1] = v[i].y;
        tile[c][p4 * 4 + 2] = v[i].z;
        tile[c][p4 * 4 + 3] = v[i].w;
    }
    __syncthreads();

    #pragma unroll
    for (int i = 0; i < 2; ++i) {
        int idx = t + i * 256;       // 0..511
        int p   = idx >> 2;          // 0..127
        int c8  = idx & 3;           // group of 8 channels
        f16x8 h;
        #pragma unroll
        for (int k = 0; k < 8; ++k)
            h[k] = (_Float16)tile[c8 * 8 + k][p];
        *((f16x8*)(o + (size_t)(pix0 + p) * CH) + c8) = h;
    }
}

// ---------------------------------------------------------------------------
// Fused kernel.
// Blocks [0, sgrid): LDS-aggregated scatter over 64 morton bins. Per block:
//   2048 points -> LDS histogram (ds_add rank) -> one padded global atomic
//   per nonzero bin (<=64 per block, 65K total) -> ~32 contiguous records
//   per (block,bin) = full-line nontemporal bucket stores.
// Blocks [sgrid, sgrid + 6144): plane transpose (BW-bound, overlaps the
//   latency-bound scatter in the same dispatch).
// ---------------------------------------------------------------------------
__global__ __launch_bounds__(256) void fused_scatter_transpose(
    const float* __restrict__ xyz,
    const float* __restrict__ p0, const float* __restrict__ p1,
    const float* __restrict__ p2, _Float16* __restrict__ tp,
    uint32_t* __restrict__ gcounts,   // NBIN counters, stride CPAD u32
    f32x4* __restrict__ buckets,
    f32x4* __restrict__ ovf, uint32_t* __restrict__ ovf_cnt,
    int npts, int sgrid)
{
    __shared__ __align__(16) char smem[CH * 129 * sizeof(float)];  // 16.5 KB
    const int bid = (int)blockIdx.x;
    const int t   = (int)threadIdx.x;

    if (bid < sgrid) {
        // ---- LDS-aggregated scatter ----
        uint32_t* lhist = (uint32_t*)smem;          // [NBIN]
        uint32_t* lbase = lhist + NBIN;             // [NBIN]
        if (t < NBIN) lhist[t] = 0u;
        __syncthreads();

        const int gi0 = bid * PPB + t * 8;
        float buf[24];
        uint32_t key[8], rank[8];

        if (gi0 + 8 <= npts) {
            const f32x4* s4 = (const f32x4*)(xyz + (size_t)gi0 * 3);
            #pragma unroll
            for (int i = 0; i < 6; ++i) {
                f32x4 v = s4[i];
                buf[4 * i + 0] = v.x; buf[4 * i + 1] = v.y;
                buf[4 * i + 2] = v.z; buf[4 * i + 3] = v.w;
            }
            #pragma unroll
            for (int j = 0; j < 8; ++j)
                key[j] = morton6(buf[3 * j], buf[3 * j + 1], buf[3 * j + 2]);
        } else {
            #pragma unroll
            for (int j = 0; j < 8; ++j) {
                if (gi0 + j < npts) {
                    buf[3 * j + 0] = xyz[(size_t)(gi0 + j) * 3 + 0];
                    buf[3 * j + 1] = xyz[(size_t)(gi0 + j) * 3 + 1];
                    buf[3 * j + 2] = xyz[(size_t)(gi0 + j) * 3 + 2];
                    key[j] = morton6(buf[3 * j], buf[3 * j + 1], buf[3 * j + 2]);
                } else {
                    key[j] = 0xffffffffu;
                }
            }
        }

        #pragma unroll
        for (int j = 0; j < 8; ++j)
            if (key[j] != 0xffffffffu)
                rank[j] = atomicAdd(&lhist[key[j]], 1u);
        __syncthreads();

        if (t < NBIN) {
            uint32_t c = lhist[t];
            lbase[t] = c ? atomicAdd(&gcounts[(size_t)t * CPAD], c) : 0u;
        }
        __syncthreads();

        #pragma unroll
        for (int j = 0; j < 8; ++j) {
            if (key[j] == 0xffffffffu) continue;
            uint32_t k = key[j];
            uint32_t pos = lbase[k] + rank[j];
            f32x4 r;
            r.x = buf[3 * j]; r.y = buf[3 * j + 1]; r.z = buf[3 * j + 2];
            r.w = __int_as_float(gi0 + j);
            if (pos < BCAP) {
                __builtin_nontemporal_store(r, &buckets[(size_t)k * BCAP + pos]);
            } else {
                uint32_t o = atomicAdd(ovf_cnt, 1u);
                ovf[o] = r;
            }
        }
    } else {
        // ---- transpose ----
        float (*tile)[129] = (float (*)[129])smem;
        int tid    = bid - sgrid;          // 0..6143
        int plane  = tid >> 11;            // /2048
        int tile_i = tid & 2047;
        const float* in = (plane == 0) ? p0 : ((plane == 1) ? p1 : p2);
        _Float16* o = tp + (size_t)plane * NPIX * CH;
        transpose_tile(in, o, tile_i * 128, t, tile);
    }
}

// ---------------------------------------------------------------------------
// Bucket gather: grid = 8 XCDs x BPX bins x CHUNKS. XCD k owns morton bins
// [8k, 8k+8) (a 2x2x2 cube); seq walks bin-by-bin so each XCD's in-flight
// blocks sit inside ~1-2 bins whose 3 MB projection set fits its 4 MB L2.
// 4 lanes/point, 64 points/pass, 256 points/block.
// ---------------------------------------------------------------------------
__global__ __launch_bounds__(256) void bucket_gather(
    const f32x4* __restrict__ buckets, const uint32_t* __restrict__ gcounts,
    const _Float16* __restrict__ tp, float* __restrict__ out)
{
    int bid   = (int)blockIdx.x;        // 0 .. 8*BPX*CHUNKS-1
    int xcd   = bid & 7;
    int seq   = bid >> 3;               // 0 .. BPX*CHUNKS-1
    int binin = seq / CHUNKS;
    int chunk = seq - binin * CHUNKS;
    int bin   = xcd * BPX + binin;

    int cnt = (int)gcounts[(size_t)bin * CPAD];
    if (cnt > BCAP) cnt = BCAP;
    int p0 = chunk * 256;
    if (p0 >= cnt) return;
    int pend = min(p0 + 256, cnt);

    int t  = (int)threadIdx.x;
    int s  = t >> 2;
    int c8 = t & 3;
    const f32x4* bk = buckets + (size_t)bin * BCAP;

    for (int p = p0 + s; p < pend; p += 64) {
        f32x4 r = bk[p];
        f32x8 acc = triplane_sample(tp, r.x, r.y, r.z, c8);
        store_point(out, __float_as_int(r.w), c8, acc);
    }
}

// Overflow cleanup (normally empty; grid-stride covers any count).
__global__ __launch_bounds__(256) void overflow_gather(
    const f32x4* __restrict__ ovf, const uint32_t* __restrict__ ovf_cnt,
    const _Float16* __restrict__ tp, float* __restrict__ out)
{
    long long total = (long long)(*ovf_cnt) * 4;
    for (long long gid = (long long)blockIdx.x * 256 + threadIdx.x;
         gid < total; gid += (long long)gridDim.x * 256) {
        int i  = (int)(gid >> 2);
        int c8 = (int)(gid & 3);
        f32x4 r = ovf[i];
        f32x8 acc = triplane_sample(tp, r.x, r.y, r.z, c8);
        store_point(out, __float_as_int(r.w), c8, acc);
    }
}

// ---------------------------------------------------------------------------
// Unsorted fallback gather (ws fits planes but not buckets).
// ---------------------------------------------------------------------------
__global__ __launch_bounds__(256) void triplane_gather_f16(
    const float* __restrict__ xyz, const _Float16* __restrict__ tp,
    float* __restrict__ out, int npts)
{
    int gid = blockIdx.x * 256 + (int)threadIdx.x;
    int n  = gid >> 2;
    int c8 = gid & 3;
    if (n >= npts) return;

    float cx = xyz[n * 3 + 0];
    float cy = xyz[n * 3 + 1];
    float cz = xyz[n * 3 + 2];
    f32x8 acc = triplane_sample(tp, cx, cy, cz, c8);
    store_point(out, n, c8, acc);
}

// ---------------------------------------------------------------------------
// Last-resort fallback: direct gather from (C,H,W) fp32.
// ---------------------------------------------------------------------------
__global__ __launch_bounds__(256) void triplane_direct(
    const float* __restrict__ xyz,
    const float* __restrict__ p0, const float* __restrict__ p1,
    const float* __restrict__ p2, float* __restrict__ out, int npts)
{
    long long gid = (long long)blockIdx.x * 256 + threadIdx.x;
    int n = (int)(gid >> 5);
    int c = (int)(gid & 31);
    if (n >= npts) return;

    float cx = xyz[n * 3 + 0];
    float cy = xyz[n * 3 + 1];
    float cz = xyz[n * 3 + 2];
    const float* planes[3] = {p0, p1, p2};
    float wcoord[3] = {cx, cy, cz};
    float hcoord[3] = {cy, cz, cx};

    float acc = 0.0f;
    #pragma unroll
    for (int pl = 0; pl < 3; ++pl) {
        float fx = (wcoord[pl] + 1.0f) * (0.5f * RES) - 0.5f;
        float fy = (hcoord[pl] + 1.0f) * (0.5f * RES) - 0.5f;
        float x0 = floorf(fx), y0 = floorf(fy);
        float wx1 = fx - x0, wy1 = fy - y0;
        float wx0 = 1.0f - wx1, wy0 = 1.0f - wy1;
        int ix0 = (int)x0, iy0 = (int)y0;
        int ix1 = ix0 + 1, iy1 = iy0 + 1;
        if (ix0 < 0 || ix0 >= RES) wx0 = 0.0f;
        if (ix1 < 0 || ix1 >= RES) wx1 = 0.0f;
        if (iy0 < 0 || iy0 >= RES) wy0 = 0.0f;
        if (iy1 < 0 || iy1 >= RES) wy1 = 0.0f;
        int jx0 = min(max(ix0, 0), RES - 1);
        int jx1 = min(max(ix1, 0), RES - 1);
        int jy0 = min(max(iy0, 0), RES - 1);
        int jy1 = min(max(iy1, 0), RES - 1);

        const float* pc = planes[pl] + (size_t)c * NPIX;
        float v00 = pc[jy0 * RES + jx0];
        float v01 = pc[jy0 * RES + jx1];
        float v10 = pc[jy1 * RES + jx0];
        float v11 = pc[jy1 * RES + jx1];
        acc += (wy0 * wx0) * v00 + (wy0 * wx1) * v01 +
               (wy1 * wx0) * v10 + (wy1 * wx1) * v11;
    }
    out[(size_t)n * CH + c] = acc;
}

extern "C" void kernel_launch(void* const* d_in, const int* in_sizes, int n_in,
                              void* d_out, int out_size, void* d_ws, size_t ws_size,
                              hipStream_t stream) {
    const float* xyz = (const float*)d_in[0];
    const float* Txy = (const float*)d_in[1];
    const float* Tyz = (const float*)d_in[2];
    const float* Tzx = (const float*)d_in[3];
    float* out = (float*)d_out;
    const int npts = in_sizes[0] / 3;

    const size_t planes_b  = (size_t)3 * NPIX * CH * sizeof(_Float16);   // 48 MB
    const size_t buckets_b = (size_t)NBIN * BCAP * sizeof(f32x4);        // 35.7 MB
    const size_t ovf_b     = (size_t)npts * sizeof(f32x4);               // 32 MB
    const size_t cnt_b     = (size_t)(NBIN * CPAD + 1) * sizeof(uint32_t); // 8 KB + 4
    const size_t need_bkt  = planes_b + buckets_b + ovf_b + cnt_b;       // ~116 MB

    const int TGRID = 6144;   // 2048 tiles x 3 planes (128 px / tile)

    if (ws_size >= need_bkt) {
        _Float16* tp      = (_Float16*)d_ws;
        f32x4*    buckets = (f32x4*)((char*)d_ws + planes_b);
        f32x4*    ovf     = (f32x4*)((char*)d_ws + planes_b + buckets_b);
        uint32_t* gcounts = (uint32_t*)((char*)d_ws + planes_b + buckets_b + ovf_b);
        uint32_t* ovf_cnt = gcounts + NBIN * CPAD;

        hipMemsetAsync(gcounts, 0, cnt_b, stream);

        int sgrid = (npts + PPB - 1) / PPB;   // 1024 for 2M points
        fused_scatter_transpose<<<sgrid + TGRID, 256, 0, stream>>>(
            xyz, Txy, Tyz, Tzx, tp, gcounts, buckets, ovf, ovf_cnt, npts, sgrid);

        bucket_gather<<<8 * BPX * CHUNKS, 256, 0, stream>>>(buckets, gcounts, tp, out);
        overflow_gather<<<128, 256, 0, stream>>>(ovf, ovf_cnt, tp, out);
    } else if (ws_size >= planes_b) {
        _Float16* tp = (_Float16*)d_ws;
        fused_scatter_transpose<<<TGRID, 256, 0, stream>>>(
            xyz, Txy, Tyz, Tzx, tp, (uint32_t*)tp, (f32x4*)tp, (f32x4*)tp,
            (uint32_t*)tp, 0, 0);   // sgrid=0 -> transpose only
        long long total = (long long)npts * 4;
        triplane_gather_f16<<<(int)((total + 255) / 256), 256, 0, stream>>>(
            xyz, tp, out, npts);
    } else {
        long long total = (long long)npts * 32;
        triplane_direct<<<(int)((total + 255) / 256), 256, 0, stream>>>(
            xyz, Txy, Tyz, Tzx, out, npts);
    }
}

// Round 6
// 471.750 us; speedup vs baseline: 1.2178x; 1.2178x over previous
//
#include <hip/hip_runtime.h>

#define RES 512
#define NPIX (RES * RES)   // 262144 texels per plane
#define CH 32
#define NBIN 512           // 8x8x8 morton bins (9-bit key), 64-texel cells
#define BCAP 4608          // bin capacity; mean 4096 -> mean+8sigma
#define PPB 8192           // points per scatter block (32 per thread)
#define CPAD 32            // u32 padding per global counter (128 B line each)
#define CHUNKS 18          // BCAP / 256

typedef float f32x4 __attribute__((ext_vector_type(4)));
typedef float f32x8 __attribute__((ext_vector_type(8)));
typedef _Float16 f16x8 __attribute__((ext_vector_type(8)));

// ---------------------------------------------------------------------------
// Shared bilinear sampler: accumulates all 3 planes for one (point, c8) lane.
// Arithmetic identical to the verified round-0 kernel (absmax unchanged).
// ---------------------------------------------------------------------------
__device__ __forceinline__ f32x8 triplane_sample(
    const _Float16* __restrict__ tp, float cx, float cy, float cz, int c8)
{
    // plane 0 (T_xy): W<-x H<-y ; plane 1 (T_yz): W<-y H<-z ; plane 2 (T_zx): W<-z H<-x
    float wcoord[3] = {cx, cy, cz};
    float hcoord[3] = {cy, cz, cx};
    f32x8 acc = {0.f, 0.f, 0.f, 0.f, 0.f, 0.f, 0.f, 0.f};

    #pragma unroll
    for (int pl = 0; pl < 3; ++pl) {
        const _Float16* __restrict__ tpp = tp + (size_t)pl * NPIX * CH;
        float fx = (wcoord[pl] + 1.0f) * (0.5f * RES) - 0.5f;
        float fy = (hcoord[pl] + 1.0f) * (0.5f * RES) - 0.5f;
        float x0 = floorf(fx), y0 = floorf(fy);
        float wx1 = fx - x0, wy1 = fy - y0;
        float wx0 = 1.0f - wx1, wy0 = 1.0f - wy1;
        int ix0 = (int)x0, iy0 = (int)y0;
        int ix1 = ix0 + 1, iy1 = iy0 + 1;
        if (ix0 < 0 || ix0 >= RES) wx0 = 0.0f;
        if (ix1 < 0 || ix1 >= RES) wx1 = 0.0f;
        if (iy0 < 0 || iy0 >= RES) wy0 = 0.0f;
        if (iy1 < 0 || iy1 >= RES) wy1 = 0.0f;
        int jx0 = min(max(ix0, 0), RES - 1);
        int jx1 = min(max(ix1, 0), RES - 1);
        int jy0 = min(max(iy0, 0), RES - 1);
        int jy1 = min(max(iy1, 0), RES - 1);

        const f16x8* r0 = (const f16x8*)(tpp + (size_t)(jy0 * RES) * CH) + c8;
        const f16x8* r1 = (const f16x8*)(tpp + (size_t)(jy1 * RES) * CH) + c8;
        f16x8 v00 = r0[jx0 * (CH / 8)];
        f16x8 v01 = r0[jx1 * (CH / 8)];
        f16x8 v10 = r1[jx0 * (CH / 8)];
        f16x8 v11 = r1[jx1 * (CH / 8)];

        acc += (wy0 * wx0) * __builtin_convertvector(v00, f32x8)
             + (wy0 * wx1) * __builtin_convertvector(v01, f32x8)
             + (wy1 * wx0) * __builtin_convertvector(v10, f32x8)
             + (wy1 * wx1) * __builtin_convertvector(v11, f32x8);
    }
    return acc;
}

__device__ __forceinline__ void store_point(
    float* __restrict__ out, int oid, int c8, f32x8 acc)
{
    float* op = out + (size_t)oid * CH + c8 * 8;
    f32x4 lo = {acc.s0, acc.s1, acc.s2, acc.s3};
    f32x4 hi = {acc.s4, acc.s5, acc.s6, acc.s7};
    __builtin_nontemporal_store(lo, (f32x4*)op);
    __builtin_nontemporal_store(hi, (f32x4*)(op + 4));
}

// 9-bit morton key: 3 bits/axis over 8x8x8 bins.
__device__ __forceinline__ uint32_t morton9(float x, float y, float z)
{
    int xi = min(max((int)((x + 1.0f) * 4.0f), 0), 7);
    int yi = min(max((int)((y + 1.0f) * 4.0f), 0), 7);
    int zi = min(max((int)((z + 1.0f) * 4.0f), 0), 7);
    uint32_t k = 0;
    #pragma unroll
    for (int b = 0; b < 3; ++b) {
        k |= ((uint32_t)((xi >> b) & 1)) << (3 * b + 0);
        k |= ((uint32_t)((yi >> b) & 1)) << (3 * b + 1);
        k |= ((uint32_t)((zi >> b) & 1)) << (3 * b + 2);
    }
    return k;
}

// ---------------------------------------------------------------------------
// Transpose tile body: (C,H,W) fp32 -> (H,W,C) fp16, 32 ch x 128 px per block.
// ---------------------------------------------------------------------------
__device__ __forceinline__ void transpose_tile(
    const float* __restrict__ in, _Float16* __restrict__ o, int pix0, int t,
    float tile[CH][129])
{
    f32x4 v[4];
    #pragma unroll
    for (int i = 0; i < 4; ++i) {
        int idx = t + i * 256;       // 0..1023
        int c   = idx >> 5;          // 0..31
        int p4  = idx & 31;          // float4 index within 128 pixels
        v[i] = *(const f32x4*)(in + (size_t)c * NPIX + pix0 + p4 * 4);
    }
    #pragma unroll
    for (int i = 0; i < 4; ++i) {
        int idx = t + i * 256;
        int c   = idx >> 5;
        int p4  = idx & 31;
        tile[c][p4 * 4 + 0] = v[i].x;
        tile[c][p4 * 4 + 1] = v[i].y;
        tile[c][p4 * 4 + 2] = v[i].z;
        tile[c][p4 * 4 + 3] = v[i].w;
    }
    __syncthreads();

    #pragma unroll
    for (int i = 0; i < 2; ++i) {
        int idx = t + i * 256;       // 0..511
        int p   = idx >> 2;          // 0..127
        int c8  = idx & 3;           // group of 8 channels
        f16x8 h;
        #pragma unroll
        for (int k = 0; k < 8; ++k)
            h[k] = (_Float16)tile[c8 * 8 + k][p];
        *((f16x8*)(o + (size_t)(pix0 + p) * CH) + c8) = h;
    }
}

// ---------------------------------------------------------------------------
// Fused kernel.
// Blocks [0, sgrid): LDS-aggregated scatter, 8192 points/block in 4
//   sub-rounds of 8 pts/thread. Single LDS histogram across all 32
//   points/thread -> one padded global atomic per nonzero (block,bin)
//   (131K total, 4x fewer than round 3) and ~16 contiguous records per
//   (block,bin) = full 256 B runs that merge in the CU's XCD L2 before
//   writeback. Pass B re-reads the block's 96 KB xyz slice (L2-hot);
//   persistent state is 32 packed (key<<13|rank) regs.
// Blocks [sgrid, sgrid + 6144): plane transpose (BW-bound, overlaps the
//   latency-bound scatter in the same dispatch).
// ---------------------------------------------------------------------------
__global__ __launch_bounds__(256) void fused_scatter_transpose(
    const float* __restrict__ xyz,
    const float* __restrict__ p0, const float* __restrict__ p1,
    const float* __restrict__ p2, _Float16* __restrict__ tp,
    uint32_t* __restrict__ gcounts,   // NBIN counters, stride CPAD u32
    f32x4* __restrict__ buckets,
    f32x4* __restrict__ ovf, uint32_t* __restrict__ ovf_cnt,
    int npts, int sgrid)
{
    __shared__ __align__(16) char smem[CH * 129 * sizeof(float)];  // 16.5 KB
    const int bid = (int)blockIdx.x;
    const int t   = (int)threadIdx.x;

    if (bid < sgrid) {
        // ---- LDS-aggregated scatter, PPB = 8192 ----
        uint32_t* lhist = (uint32_t*)smem;          // [NBIN]
        uint32_t* gbase = lhist + NBIN;             // [NBIN]
        #pragma unroll
        for (int k = t; k < NBIN; k += 256) lhist[k] = 0u;
        __syncthreads();

        // Pass A: histogram + per-point rank. packed = key<<13 | rank
        // (key 9 bits, rank < 8192 fits 13 bits); 0xffffffff = invalid.
        uint32_t packed[32];
        #pragma unroll
        for (int r = 0; r < 4; ++r) {
            const int gi0 = bid * PPB + r * 2048 + t * 8;
            float buf[24];
            if (gi0 + 8 <= npts) {
                const f32x4* s4 = (const f32x4*)(xyz + (size_t)gi0 * 3);
                #pragma unroll
                for (int i = 0; i < 6; ++i) {
                    f32x4 v = s4[i];
                    buf[4 * i + 0] = v.x; buf[4 * i + 1] = v.y;
                    buf[4 * i + 2] = v.z; buf[4 * i + 3] = v.w;
                }
                #pragma unroll
                for (int j = 0; j < 8; ++j) {
                    uint32_t k = morton9(buf[3 * j], buf[3 * j + 1], buf[3 * j + 2]);
                    uint32_t rk = atomicAdd(&lhist[k], 1u);
                    packed[r * 8 + j] = (k << 13) | rk;
                }
            } else {
                #pragma unroll
                for (int j = 0; j < 8; ++j) {
                    if (gi0 + j < npts) {
                        float x = xyz[(size_t)(gi0 + j) * 3 + 0];
                        float y = xyz[(size_t)(gi0 + j) * 3 + 1];
                        float z = xyz[(size_t)(gi0 + j) * 3 + 2];
                        uint32_t k = morton9(x, y, z);
                        uint32_t rk = atomicAdd(&lhist[k], 1u);
                        packed[r * 8 + j] = (k << 13) | rk;
                    } else {
                        packed[r * 8 + j] = 0xffffffffu;
                    }
                }
            }
        }
        __syncthreads();

        // One global atomic per nonzero bin -> base of this block's run.
        #pragma unroll
        for (int k = t; k < NBIN; k += 256) {
            uint32_t c = lhist[k];
            gbase[k] = c ? atomicAdd(&gcounts[(size_t)k * CPAD], c) : 0u;
        }
        __syncthreads();

        // Pass B: re-read coords (L2-hot) and write clustered records.
        #pragma unroll
        for (int r = 0; r < 4; ++r) {
            const int gi0 = bid * PPB + r * 2048 + t * 8;
            float buf[24];
            if (gi0 + 8 <= npts) {
                const f32x4* s4 = (const f32x4*)(xyz + (size_t)gi0 * 3);
                #pragma unroll
                for (int i = 0; i < 6; ++i) {
                    f32x4 v = s4[i];
                    buf[4 * i + 0] = v.x; buf[4 * i + 1] = v.y;
                    buf[4 * i + 2] = v.z; buf[4 * i + 3] = v.w;
                }
            } else {
                #pragma unroll
                for (int j = 0; j < 8; ++j) {
                    if (gi0 + j < npts) {
                        buf[3 * j + 0] = xyz[(size_t)(gi0 + j) * 3 + 0];
                        buf[3 * j + 1] = xyz[(size_t)(gi0 + j) * 3 + 1];
                        buf[3 * j + 2] = xyz[(size_t)(gi0 + j) * 3 + 2];
                    }
                }
            }
            #pragma unroll
            for (int j = 0; j < 8; ++j) {
                uint32_t pk = packed[r * 8 + j];
                if (pk == 0xffffffffu) continue;
                uint32_t k  = pk >> 13;
                uint32_t rk = pk & 0x1fffu;
                uint32_t pos = gbase[k] + rk;
                f32x4 rec;
                rec.x = buf[3 * j]; rec.y = buf[3 * j + 1]; rec.z = buf[3 * j + 2];
                rec.w = __int_as_float(gi0 + j);
                if (pos < BCAP) {
                    buckets[(size_t)k * BCAP + pos] = rec;   // plain: let L2 merge
                } else {
                    uint32_t o = atomicAdd(ovf_cnt, 1u);
                    ovf[o] = rec;
                }
            }
        }
    } else {
        // ---- transpose ----
        float (*tile)[129] = (float (*)[129])smem;
        int tid    = bid - sgrid;          // 0..6143
        int plane  = tid >> 11;            // /2048
        int tile_i = tid & 2047;
        const float* in = (plane == 0) ? p0 : ((plane == 1) ? p1 : p2);
        _Float16* o = tp + (size_t)plane * NPIX * CH;
        transpose_tile(in, o, tile_i * 128, t, tile);
    }
}

// ---------------------------------------------------------------------------
// Bucket gather (round-3 verified geometry): grid = NBIN x CHUNKS. XCD k
// owns morton bins [k*64, (k+1)*64); seq walks bin-by-bin so in-flight
// blocks sit in ~1-2 bins whose 768 KB projection set is L2-hot.
// 4 lanes/point, 64 points/pass, 256 points/block.
// ---------------------------------------------------------------------------
__global__ __launch_bounds__(256) void bucket_gather(
    const f32x4* __restrict__ buckets, const uint32_t* __restrict__ gcounts,
    const _Float16* __restrict__ tp, float* __restrict__ out)
{
    int bid = (int)blockIdx.x;                       // 0 .. NBIN*CHUNKS-1
    int swz = (bid & 7) * (NBIN * CHUNKS / 8) + (bid >> 3);  // bijective: %8==0
    int bin = swz / CHUNKS;
    int chunk = swz - bin * CHUNKS;
    int cnt = (int)gcounts[(size_t)bin * CPAD];
    if (cnt > BCAP) cnt = BCAP;
    int p0 = chunk * 256;
    if (p0 >= cnt) return;
    int pend = min(p0 + 256, cnt);

    int t  = (int)threadIdx.x;
    int s  = t >> 2;
    int c8 = t & 3;
    const f32x4* bk = buckets + (size_t)bin * BCAP;

    for (int p = p0 + s; p < pend; p += 64) {
        f32x4 r = bk[p];
        f32x8 acc = triplane_sample(tp, r.x, r.y, r.z, c8);
        store_point(out, __float_as_int(r.w), c8, acc);
    }
}

// Overflow cleanup (normally empty; grid-stride covers any count).
__global__ __launch_bounds__(256) void overflow_gather(
    const f32x4* __restrict__ ovf, const uint32_t* __restrict__ ovf_cnt,
    const _Float16* __restrict__ tp, float* __restrict__ out)
{
    long long total = (long long)(*ovf_cnt) * 4;
    for (long long gid = (long long)blockIdx.x * 256 + threadIdx.x;
         gid < total; gid += (long long)gridDim.x * 256) {
        int i  = (int)(gid >> 2);
        int c8 = (int)(gid & 3);
        f32x4 r = ovf[i];
        f32x8 acc = triplane_sample(tp, r.x, r.y, r.z, c8);
        store_point(out, __float_as_int(r.w), c8, acc);
    }
}

// ---------------------------------------------------------------------------
// Unsorted fallback gather (ws fits planes but not buckets).
// ---------------------------------------------------------------------------
__global__ __launch_bounds__(256) void triplane_gather_f16(
    const float* __restrict__ xyz, const _Float16* __restrict__ tp,
    float* __restrict__ out, int npts)
{
    int gid = blockIdx.x * 256 + (int)threadIdx.x;
    int n  = gid >> 2;
    int c8 = gid & 3;
    if (n >= npts) return;

    float cx = xyz[n * 3 + 0];
    float cy = xyz[n * 3 + 1];
    float cz = xyz[n * 3 + 2];
    f32x8 acc = triplane_sample(tp, cx, cy, cz, c8);
    store_point(out, n, c8, acc);
}

// ---------------------------------------------------------------------------
// Last-resort fallback: direct gather from (C,H,W) fp32.
// ---------------------------------------------------------------------------
__global__ __launch_bounds__(256) void triplane_direct(
    const float* __restrict__ xyz,
    const float* __restrict__ p0, const float* __restrict__ p1,
    const float* __restrict__ p2, float* __restrict__ out, int npts)
{
    long long gid = (long long)blockIdx.x * 256 + threadIdx.x;
    int n = (int)(gid >> 5);
    int c = (int)(gid & 31);
    if (n >= npts) return;

    float cx = xyz[n * 3 + 0];
    float cy = xyz[n * 3 + 1];
    float cz = xyz[n * 3 + 2];
    const float* planes[3] = {p0, p1, p2};
    float wcoord[3] = {cx, cy, cz};
    float hcoord[3] = {cy, cz, cx};

    float acc = 0.0f;
    #pragma unroll
    for (int pl = 0; pl < 3; ++pl) {
        float fx = (wcoord[pl] + 1.0f) * (0.5f * RES) - 0.5f;
        float fy = (hcoord[pl] + 1.0f) * (0.5f * RES) - 0.5f;
        float x0 = floorf(fx), y0 = floorf(fy);
        float wx1 = fx - x0, wy1 = fy - y0;
        float wx0 = 1.0f - wx1, wy0 = 1.0f - wy1;
        int ix0 = (int)x0, iy0 = (int)y0;
        int ix1 = ix0 + 1, iy1 = iy0 + 1;
        if (ix0 < 0 || ix0 >= RES) wx0 = 0.0f;
        if (ix1 < 0 || ix1 >= RES) wx1 = 0.0f;
        if (iy0 < 0 || iy0 >= RES) wy0 = 0.0f;
        if (iy1 < 0 || iy1 >= RES) wy1 = 0.0f;
        int jx0 = min(max(ix0, 0), RES - 1);
        int jx1 = min(max(ix1, 0), RES - 1);
        int jy0 = min(max(iy0, 0), RES - 1);
        int jy1 = min(max(iy1, 0), RES - 1);

        const float* pc = planes[pl] + (size_t)c * NPIX;
        float v00 = pc[jy0 * RES + jx0];
        float v01 = pc[jy0 * RES + jx1];
        float v10 = pc[jy1 * RES + jx0];
        float v11 = pc[jy1 * RES + jx1];
        acc += (wy0 * wx0) * v00 + (wy0 * wx1) * v01 +
               (wy1 * wx0) * v10 + (wy1 * wx1) * v11;
    }
    out[(size_t)n * CH + c] = acc;
}

extern "C" void kernel_launch(void* const* d_in, const int* in_sizes, int n_in,
                              void* d_out, int out_size, void* d_ws, size_t ws_size,
                              hipStream_t stream) {
    const float* xyz = (const float*)d_in[0];
    const float* Txy = (const float*)d_in[1];
    const float* Tyz = (const float*)d_in[2];
    const float* Tzx = (const float*)d_in[3];
    float* out = (float*)d_out;
    const int npts = in_sizes[0] / 3;

    const size_t planes_b  = (size_t)3 * NPIX * CH * sizeof(_Float16);   // 48 MB
    const size_t buckets_b = (size_t)NBIN * BCAP * sizeof(f32x4);        // 36 MB
    const size_t ovf_b     = (size_t)npts * sizeof(f32x4);               // 32 MB
    const size_t cnt_b     = (size_t)(NBIN * CPAD + 1) * sizeof(uint32_t); // 64 KB + 4
    const size_t need_bkt  = planes_b + buckets_b + ovf_b + cnt_b;       // ~116 MB

    const int TGRID = 6144;   // 2048 tiles x 3 planes (128 px / tile)

    if (ws_size >= need_bkt) {
        _Float16* tp      = (_Float16*)d_ws;
        f32x4*    buckets = (f32x4*)((char*)d_ws + planes_b);
        f32x4*    ovf     = (f32x4*)((char*)d_ws + planes_b + buckets_b);
        uint32_t* gcounts = (uint32_t*)((char*)d_ws + planes_b + buckets_b + ovf_b);
        uint32_t* ovf_cnt = gcounts + NBIN * CPAD;

        hipMemsetAsync(gcounts, 0, cnt_b, stream);

        int sgrid = (npts + PPB - 1) / PPB;   // 256 for 2M points
        fused_scatter_transpose<<<sgrid + TGRID, 256, 0, stream>>>(
            xyz, Txy, Tyz, Tzx, tp, gcounts, buckets, ovf, ovf_cnt, npts, sgrid);

        bucket_gather<<<NBIN * CHUNKS, 256, 0, stream>>>(buckets, gcounts, tp, out);
        overflow_gather<<<128, 256, 0, stream>>>(ovf, ovf_cnt, tp, out);
    } else if (ws_size >= planes_b) {
        _Float16* tp = (_Float16*)d_ws;
        fused_scatter_transpose<<<TGRID, 256, 0, stream>>>(
            xyz, Txy, Tyz, Tzx, tp, (uint32_t*)tp, (f32x4*)tp, (f32x4*)tp,
            (uint32_t*)tp, 0, 0);   // sgrid=0 -> transpose only
        long long total = (long long)npts * 4;
        triplane_gather_f16<<<(int)((total + 255) / 256), 256, 0, stream>>>(
            xyz, tp, out, npts);
    } else {
        long long total = (long long)npts * 32;
        triplane_direct<<<(int)((total + 255) / 256), 256, 0, stream>>>(
            xyz, Txy, Tyz, Tzx, out, npts);
    }
}